// Round 8
// baseline (1391.196 us; speedup 1.0000x reference)
//
#include <hip/hip_runtime.h>

#define KDIM 8192
#define NDIM 16384
#define BDIM 16
#define NBLK 8                        // KDIM/1024 scale blocks per row
#define TN 8                          // output rows per wave
#define WAVES 4
#define ROWS_PER_BLOCK (WAVES * TN)   // 32
#define KC 256                        // k-elements per chunk
#define NCHUNK (KDIM / KC)            // 32

// global->LDS direct copy, 16B/lane: LDS dest wave-uniform, global src per-lane.
__device__ __forceinline__ void gload_lds16(const float* g, float* l) {
    __builtin_amdgcn_global_load_lds(
        (const __attribute__((address_space(1))) unsigned int*)(uintptr_t)g,
        (__attribute__((address_space(3))) unsigned int*)(uintptr_t)l,
        16, 0, 0);
}

// Block owns 32 N-rows over full K (4 waves x TN=8). x chunk (16x256 f32)
// double-buffered in LDS, shared by all waves (LDS-pipe cost ~1/TN); W
// coalesced int4 loads, register double-buffered one compute phase (~1100cy)
// ahead of use so the barrier vmcnt drain is covered.
__global__ void int8lin_kernel(
    const float* __restrict__ x,
    const int* __restrict__ qw,
    const float* __restrict__ scales,
    const float* __restrict__ bias,
    float* __restrict__ out)
{
    __shared__ float xbuf[2][BDIM][KC];   // 2 x 16 KB

    const int lane = threadIdx.x & 63;
    const int wave = threadIdx.x >> 6;
    const int n0 = blockIdx.x * ROWS_PER_BLOCK + wave * TN;
    const int kbase = lane * 4;

    float acc[BDIM][TN];
#pragma unroll
    for (int i = 0; i < BDIM; ++i)
#pragma unroll
        for (int j = 0; j < TN; ++j) acc[i][j] = 0.f;

    // Stage x chunk c into xbuf[pb]: wave w stages batch rows 4w..4w+3.
    auto STAGE = [&](int c, int pb) {
#pragma unroll
        for (int q = 0; q < 4; ++q) {
            const int i = wave * 4 + q;
            gload_lds16(x + (size_t)i * KDIM + c * KC + kbase, &xbuf[pb][i][0]);
        }
    };

    auto LOADW = [&](int4* w, int c) {
#pragma unroll
        for (int j = 0; j < TN; ++j)
            w[j] = *reinterpret_cast<const int4*>(qw + (size_t)(n0 + j) * KDIM + c * KC + kbase);
    };

    auto COMPUTE = [&](const int4* w, int c, int pb) {
        float s[TN], wf[TN][4];
#pragma unroll
        for (int j = 0; j < TN; ++j)
            s[j] = scales[(size_t)(n0 + j) * NBLK + (c >> 2)];
#pragma unroll
        for (int j = 0; j < TN; ++j) {
            wf[j][0] = (float)w[j].x * s[j];
            wf[j][1] = (float)w[j].y * s[j];
            wf[j][2] = (float)w[j].z * s[j];
            wf[j][3] = (float)w[j].w * s[j];
        }
#pragma unroll
        for (int i = 0; i < BDIM; ++i) {
            const float4 xv = *reinterpret_cast<const float4*>(&xbuf[pb][i][kbase]);
#pragma unroll
            for (int j = 0; j < TN; ++j) {
                acc[i][j] = fmaf(xv.x, wf[j][0], acc[i][j]);
                acc[i][j] = fmaf(xv.y, wf[j][1], acc[i][j]);
                acc[i][j] = fmaf(xv.z, wf[j][2], acc[i][j]);
                acc[i][j] = fmaf(xv.w, wf[j][3], acc[i][j]);
            }
        }
    };

    int4 wA[TN], wB[TN];
    STAGE(0, 0);
    LOADW(wA, 0);

#pragma unroll 1
    for (int c = 0; c < NCHUNK; c += 2) {
        __syncthreads();                 // xbuf[0] (chunk c) ready; wA landed
        STAGE(c + 1, 1);                 // x[c+1] + wB[c+1] fly under compute
        LOADW(wB, c + 1);
        COMPUTE(wA, c, 0);

        __syncthreads();                 // xbuf[1] ready; wB landed
        if (c + 2 < NCHUNK) {
            STAGE(c + 2, 0);
            LOADW(wA, c + 2);
        }
        COMPUTE(wB, c + 1, 1);
    }

    // 64-lane butterfly reduction; lane 0 stores its wave's 16xTN tile.
#pragma unroll
    for (int i = 0; i < BDIM; ++i)
#pragma unroll
        for (int j = 0; j < TN; ++j) {
            float v = acc[i][j];
#pragma unroll
            for (int off = 32; off >= 1; off >>= 1) v += __shfl_xor(v, off, 64);
            acc[i][j] = v;
        }

    if (lane == 0) {
#pragma unroll
        for (int j = 0; j < TN; ++j) {
            const float b = bias[n0 + j];
#pragma unroll
            for (int i = 0; i < BDIM; ++i)
                out[(size_t)i * NDIM + (n0 + j)] = acc[i][j] + b;
        }
    }
}

extern "C" void kernel_launch(void* const* d_in, const int* in_sizes, int n_in,
                              void* d_out, int out_size, void* d_ws, size_t ws_size,
                              hipStream_t stream) {
    const float* x      = (const float*)d_in[0];
    const int*   qw     = (const int*)d_in[1];
    const float* scales = (const float*)d_in[2];
    const float* bias   = (const float*)d_in[3];
    float*       out    = (float*)d_out;

    dim3 grid(NDIM / ROWS_PER_BLOCK);   // 512 blocks = 2 per CU
    dim3 block(256);                     // 4 waves
    int8lin_kernel<<<grid, block, 0, stream>>>(x, qw, scales, bias, out);
}

// Round 9
// 445.744 us; speedup vs baseline: 3.1211x; 3.1211x over previous
//
#include <hip/hip_runtime.h>

#define KDIM 8192
#define NDIM 16384
#define BDIM 16
#define NBLK 8                        // KDIM/1024 scale blocks per row
#define TN 8                          // output rows per wave
#define WAVES 4
#define ROWS_PER_BLOCK (WAVES * TN)   // 32
#define KC 256                        // k-elements per chunk
#define NCHUNK (KDIM / KC)            // 32

// global->LDS direct copy, 16B/lane: LDS dest wave-uniform, global src per-lane.
__device__ __forceinline__ void gload_lds16(const float* g, float* l) {
    __builtin_amdgcn_global_load_lds(
        (const __attribute__((address_space(1))) unsigned int*)(uintptr_t)g,
        (__attribute__((address_space(3))) unsigned int*)(uintptr_t)l,
        16, 0, 0);
}

// Block owns 32 N-rows over full K (4 waves x TN=8). x chunk (16x256 f32)
// double-buffered in LDS, shared by all waves (LDS-pipe cost ~1/TN); W
// coalesced int4 loads, register double-buffered one compute phase ahead.
// launch_bounds(256,2): VGPR cap 256 >= ~240 live set. NO cap / omission
// spills (round 4: cap 128 -> 2.3GB scratch; round 8: default 64 -> 5GB).
__global__ __launch_bounds__(256, 2) void int8lin_kernel(
    const float* __restrict__ x,
    const int* __restrict__ qw,
    const float* __restrict__ scales,
    const float* __restrict__ bias,
    float* __restrict__ out)
{
    __shared__ float xbuf[2][BDIM][KC];   // 2 x 16 KB

    const int lane = threadIdx.x & 63;
    const int wave = threadIdx.x >> 6;
    const int n0 = blockIdx.x * ROWS_PER_BLOCK + wave * TN;
    const int kbase = lane * 4;

    float acc[BDIM][TN];
#pragma unroll
    for (int i = 0; i < BDIM; ++i)
#pragma unroll
        for (int j = 0; j < TN; ++j) acc[i][j] = 0.f;

    // Stage x chunk c into xbuf[pb]: wave w stages batch rows 4w..4w+3.
    auto STAGE = [&](int c, int pb) {
#pragma unroll
        for (int q = 0; q < 4; ++q) {
            const int i = wave * 4 + q;
            gload_lds16(x + (size_t)i * KDIM + c * KC + kbase, &xbuf[pb][i][0]);
        }
    };

    auto LOADW = [&](int4* w, int c) {
#pragma unroll
        for (int j = 0; j < TN; ++j)
            w[j] = *reinterpret_cast<const int4*>(qw + (size_t)(n0 + j) * KDIM + c * KC + kbase);
    };

    auto COMPUTE = [&](const int4* w, int c, int pb) {
        float s[TN], wf[TN][4];
#pragma unroll
        for (int j = 0; j < TN; ++j)
            s[j] = scales[(size_t)(n0 + j) * NBLK + (c >> 2)];
#pragma unroll
        for (int j = 0; j < TN; ++j) {
            wf[j][0] = (float)w[j].x * s[j];
            wf[j][1] = (float)w[j].y * s[j];
            wf[j][2] = (float)w[j].z * s[j];
            wf[j][3] = (float)w[j].w * s[j];
        }
#pragma unroll
        for (int i = 0; i < BDIM; ++i) {
            const float4 xv = *reinterpret_cast<const float4*>(&xbuf[pb][i][kbase]);
#pragma unroll
            for (int j = 0; j < TN; ++j) {
                acc[i][j] = fmaf(xv.x, wf[j][0], acc[i][j]);
                acc[i][j] = fmaf(xv.y, wf[j][1], acc[i][j]);
                acc[i][j] = fmaf(xv.z, wf[j][2], acc[i][j]);
                acc[i][j] = fmaf(xv.w, wf[j][3], acc[i][j]);
            }
        }
    };

    int4 wA[TN], wB[TN];
    STAGE(0, 0);
    LOADW(wA, 0);

#pragma unroll 1
    for (int c = 0; c < NCHUNK; c += 2) {
        __syncthreads();                 // xbuf[0] (chunk c) ready; wA landed
        STAGE(c + 1, 1);                 // x[c+1] + wB[c+1] fly under compute
        LOADW(wB, c + 1);
        COMPUTE(wA, c, 0);

        __syncthreads();                 // xbuf[1] ready; wB landed
        if (c + 2 < NCHUNK) {
            STAGE(c + 2, 0);
            LOADW(wA, c + 2);
        }
        COMPUTE(wB, c + 1, 1);
    }

    // 64-lane butterfly reduction; lane 0 stores its wave's 16xTN tile.
#pragma unroll
    for (int i = 0; i < BDIM; ++i)
#pragma unroll
        for (int j = 0; j < TN; ++j) {
            float v = acc[i][j];
#pragma unroll
            for (int off = 32; off >= 1; off >>= 1) v += __shfl_xor(v, off, 64);
            acc[i][j] = v;
        }

    if (lane == 0) {
#pragma unroll
        for (int j = 0; j < TN; ++j) {
            const float b = bias[n0 + j];
#pragma unroll
            for (int i = 0; i < BDIM; ++i)
                out[(size_t)i * NDIM + (n0 + j)] = acc[i][j] + b;
        }
    }
}

extern "C" void kernel_launch(void* const* d_in, const int* in_sizes, int n_in,
                              void* d_out, int out_size, void* d_ws, size_t ws_size,
                              hipStream_t stream) {
    const float* x      = (const float*)d_in[0];
    const int*   qw     = (const int*)d_in[1];
    const float* scales = (const float*)d_in[2];
    const float* bias   = (const float*)d_in[3];
    float*       out    = (float*)d_out;

    dim3 grid(NDIM / ROWS_PER_BLOCK);   // 512 blocks = 2 per CU
    dim3 block(256);                     // 4 waves
    int8lin_kernel<<<grid, block, 0, stream>>>(x, qw, scales, bias, out);
}

// Round 10
// 153.238 us; speedup vs baseline: 9.0787x; 2.9088x over previous
//
#include <hip/hip_runtime.h>

#define KDIM 8192
#define NDIM 16384
#define BDIM 16
#define NBLK 8                        // KDIM/1024 scale blocks per row
#define TN 8                          // output rows per wave
#define WAVES 4
#define ROWS_PER_BLOCK (WAVES * TN)   // 32
#define KC 256                        // k-elements per chunk
#define NCHUNK (KDIM / KC)            // 32

// global->LDS direct copy, 16B/lane: LDS dest wave-uniform, global src per-lane.
__device__ __forceinline__ void gload_lds16(const float* g, float* l) {
    __builtin_amdgcn_global_load_lds(
        (const __attribute__((address_space(1))) unsigned int*)(uintptr_t)g,
        (__attribute__((address_space(3))) unsigned int*)(uintptr_t)l,
        16, 0, 0);
}

// Block owns 32 N-rows over full K (4 waves x TN=8). x chunk (16x256 f32)
// double-buffered in LDS, shared by all waves (LDS-pipe cost ~1/TN); W
// coalesced int4 loads, register double-buffered one compute phase ahead.
//
// MEASURED launch_bounds table (this toolchain): (256,4)->64 VGPR,
// (256,2)->128, none->64 -- all spill this structure (rounds 4/8/9).
// (256) with no min-waves arg -> live-set-driven allocation, no spill
// (round 7). DO NOT add a min-waves argument.
__global__ __launch_bounds__(256) void int8lin_kernel(
    const float* __restrict__ x,
    const int* __restrict__ qw,
    const float* __restrict__ scales,
    const float* __restrict__ bias,
    float* __restrict__ out)
{
    __shared__ float xbuf[2][BDIM][KC];   // 2 x 16 KB

    const int lane = threadIdx.x & 63;
    const int wave = threadIdx.x >> 6;
    const int n0 = blockIdx.x * ROWS_PER_BLOCK + wave * TN;
    const int kbase = lane * 4;

    float acc[BDIM][TN];
#pragma unroll
    for (int i = 0; i < BDIM; ++i)
#pragma unroll
        for (int j = 0; j < TN; ++j) acc[i][j] = 0.f;

    // Stage x chunk c into xbuf[pb]: wave w stages batch rows 4w..4w+3.
    auto STAGE = [&](int c, int pb) {
#pragma unroll
        for (int q = 0; q < 4; ++q) {
            const int i = wave * 4 + q;
            gload_lds16(x + (size_t)i * KDIM + c * KC + kbase, &xbuf[pb][i][0]);
        }
    };

    auto LOADW = [&](int4* w, int c) {
#pragma unroll
        for (int j = 0; j < TN; ++j)
            w[j] = *reinterpret_cast<const int4*>(qw + (size_t)(n0 + j) * KDIM + c * KC + kbase);
    };

    auto COMPUTE = [&](const int4* w, int c, int pb) {
        float s[TN], wf[TN][4];
#pragma unroll
        for (int j = 0; j < TN; ++j)
            s[j] = scales[(size_t)(n0 + j) * NBLK + (c >> 2)];
#pragma unroll
        for (int j = 0; j < TN; ++j) {
            wf[j][0] = (float)w[j].x * s[j];
            wf[j][1] = (float)w[j].y * s[j];
            wf[j][2] = (float)w[j].z * s[j];
            wf[j][3] = (float)w[j].w * s[j];
        }
#pragma unroll
        for (int i = 0; i < BDIM; ++i) {
            const float4 xv = *reinterpret_cast<const float4*>(&xbuf[pb][i][kbase]);
#pragma unroll
            for (int j = 0; j < TN; ++j) {
                acc[i][j] = fmaf(xv.x, wf[j][0], acc[i][j]);
                acc[i][j] = fmaf(xv.y, wf[j][1], acc[i][j]);
                acc[i][j] = fmaf(xv.z, wf[j][2], acc[i][j]);
                acc[i][j] = fmaf(xv.w, wf[j][3], acc[i][j]);
            }
        }
    };

    int4 wA[TN], wB[TN];
    STAGE(0, 0);
    LOADW(wA, 0);

#pragma unroll 1
    for (int c = 0; c < NCHUNK; c += 2) {
        __syncthreads();                 // xbuf[0] (chunk c) ready; wA landed
        STAGE(c + 1, 1);                 // x[c+1] + wB[c+1] fly under compute
        LOADW(wB, c + 1);
        COMPUTE(wA, c, 0);

        __syncthreads();                 // xbuf[1] ready; wB landed
        if (c + 2 < NCHUNK) {
            STAGE(c + 2, 0);
            LOADW(wA, c + 2);
        }
        COMPUTE(wB, c + 1, 1);
    }

    // 64-lane butterfly reduction; lane 0 stores its wave's 16xTN tile.
#pragma unroll
    for (int i = 0; i < BDIM; ++i)
#pragma unroll
        for (int j = 0; j < TN; ++j) {
            float v = acc[i][j];
#pragma unroll
            for (int off = 32; off >= 1; off >>= 1) v += __shfl_xor(v, off, 64);
            acc[i][j] = v;
        }

    if (lane == 0) {
#pragma unroll
        for (int j = 0; j < TN; ++j) {
            const float b = bias[n0 + j];
#pragma unroll
            for (int i = 0; i < BDIM; ++i)
                out[(size_t)i * NDIM + (n0 + j)] = acc[i][j] + b;
        }
    }
}

extern "C" void kernel_launch(void* const* d_in, const int* in_sizes, int n_in,
                              void* d_out, int out_size, void* d_ws, size_t ws_size,
                              hipStream_t stream) {
    const float* x      = (const float*)d_in[0];
    const int*   qw     = (const int*)d_in[1];
    const float* scales = (const float*)d_in[2];
    const float* bias   = (const float*)d_in[3];
    float*       out    = (float*)d_out;

    dim3 grid(NDIM / ROWS_PER_BLOCK);   // 512 blocks = 2 per CU
    dim3 block(256);                     // 4 waves
    int8lin_kernel<<<grid, block, 0, stream>>>(x, qw, scales, bias, out);
}